// Round 1
// baseline (698.905 us; speedup 1.0000x reference)
//
#include <hip/hip_runtime.h>

typedef __attribute__((ext_vector_type(8))) short bh8;
typedef __attribute__((ext_vector_type(4))) float f4;

__device__ __forceinline__ unsigned short f2bf(float x) {
  unsigned int u = __float_as_uint(x);
  u += 0x7fffu + ((u >> 16) & 1u);
  return (unsigned short)(u >> 16);
}
__device__ __forceinline__ float bf2f(short x) {
  return __uint_as_float(((unsigned int)(unsigned short)x) << 16);
}

// ---------------- RoPE table ----------------
__global__ __launch_bounds__(256)
void rope_table(float* __restrict__ ct, float* __restrict__ st) {
  const int idx = blockIdx.x * 256 + threadIdx.x;   // 65536 = 2048*32
  const int s = idx >> 5, j = idx & 31;
  const float invf = expf(-0.28782313662425574f * (float)j);  // 10000^(-j/32)
  const float f = (float)s * invf;
  ct[idx] = cosf(f);
  st[idx] = sinf(f);
}

// ---------------- weight fp32 -> bf16 ----------------
__global__ __launch_bounds__(256)
void w2bf(const float* __restrict__ w, short* __restrict__ o, int n) {
  const int i = (blockIdx.x * 256 + threadIdx.x) * 4;
  if (i >= n) return;
  f4 v = *(const f4*)(w + i);
#pragma unroll
  for (int j = 0; j < 4; ++j) o[i + j] = (short)f2bf(v[j]);
}

// ---------------- LayerNorm (row=1024) ----------------
__global__ __launch_bounds__(256)
void layernorm_bf(const float* __restrict__ x, const float* __restrict__ g,
                  const float* __restrict__ be, short* __restrict__ out) {
  __shared__ float sb[4];
  const int row = blockIdx.x, t = threadIdx.x;
  const float* xr = x + (size_t)row * 1024;
  f4 v = *(const f4*)(xr + t * 4);
  float s = v[0] + v[1] + v[2] + v[3];
#pragma unroll
  for (int mk = 1; mk < 64; mk <<= 1) s += __shfl_xor(s, mk, 64);
  if ((t & 63) == 0) sb[t >> 6] = s;
  __syncthreads();
  const float mean = (sb[0] + sb[1] + sb[2] + sb[3]) * (1.0f / 1024.0f);
  __syncthreads();
  f4 d;
#pragma unroll
  for (int i = 0; i < 4; ++i) d[i] = v[i] - mean;
  float s2 = d[0] * d[0] + d[1] * d[1] + d[2] * d[2] + d[3] * d[3];
#pragma unroll
  for (int mk = 1; mk < 64; mk <<= 1) s2 += __shfl_xor(s2, mk, 64);
  if ((t & 63) == 0) sb[t >> 6] = s2;
  __syncthreads();
  const float var = (sb[0] + sb[1] + sb[2] + sb[3]) * (1.0f / 1024.0f);
  const float rstd = rsqrtf(var + 1e-5f);
  const f4 gg = *(const f4*)(g + t * 4);
  const f4 bb = *(const f4*)(be + t * 4);
#pragma unroll
  for (int i = 0; i < 4; ++i)
    out[(size_t)row * 1024 + t * 4 + i] = (short)f2bf(d[i] * rstd * gg[i] + bb[i]);
}

// ---------------- in-place RoPE on bf16 [8192,1024] ----------------
__global__ __launch_bounds__(256)
void rope_apply(short* __restrict__ qk, const float* __restrict__ ct,
                const float* __restrict__ st) {
  const int gid = blockIdx.x * 256 + threadIdx.x;  // 8192*128
  const int row = gid >> 7, chn = gid & 127;
  const int srow = row & 2047;
  const int col = chn * 8;
  const int j0 = (col & 63) >> 1;
  bh8 vv = *(const bh8*)(qk + (size_t)row * 1024 + col);
  bh8 r;
#pragma unroll
  for (int p = 0; p < 4; ++p) {
    const float e = bf2f(vv[2 * p]), od = bf2f(vv[2 * p + 1]);
    const float c = ct[srow * 32 + j0 + p], sn = st[srow * 32 + j0 + p];
    r[2 * p]     = (short)f2bf(e * c - od * sn);
    r[2 * p + 1] = (short)f2bf(e * sn + od * c);
  }
  *(bh8*)(qk + (size_t)row * 1024 + col) = r;
}

// ---------------- bf16 B^T GEMM: C[M,N] = A[M,K] * Bw[N,K]^T + bias (+res)(+relu) ----------------
template <int RELU, int RES, int OBF16>
__global__ __launch_bounds__(256)
void gemm_bt(const short* __restrict__ A, const short* __restrict__ Bw,
             const float* __restrict__ bias, const float* __restrict__ res,
             short* __restrict__ Cb, float* __restrict__ Cf,
             int M, int N, int K) {
  __shared__ short As[128 * 40];
  __shared__ short Bs[128 * 40];
  const int t = threadIdx.x;
  const int lane = t & 63;
  const int w = t >> 6, wr = w >> 1, wc = w & 1;
  const int bm = blockIdx.x, bn = blockIdx.y;
  const int rA = t >> 2, ch = t & 3;
  f4 acc[4][4] = {};
  const short* Ag = A + (size_t)(bm * 128 + rA) * K + ch * 8;
  const short* Bg = Bw + (size_t)(bn * 128 + rA) * K + ch * 8;
  for (int kt = 0; kt < K; kt += 32) {
    __syncthreads();
#pragma unroll
    for (int p = 0; p < 2; ++p) {
      bh8 va = *(const bh8*)(Ag + (size_t)p * 64 * K + kt);
      bh8 vb = *(const bh8*)(Bg + (size_t)p * 64 * K + kt);
      *(bh8*)(&As[(p * 64 + rA) * 40 + ch * 8]) = va;
      *(bh8*)(&Bs[(p * 64 + rA) * 40 + ch * 8]) = vb;
    }
    __syncthreads();
    bh8 af[4], bf[4];
#pragma unroll
    for (int m = 0; m < 4; ++m)
      af[m] = *(const bh8*)(&As[(wr * 64 + m * 16 + (lane & 15)) * 40 + (lane >> 4) * 8]);
#pragma unroll
    for (int n = 0; n < 4; ++n)
      bf[n] = *(const bh8*)(&Bs[(wc * 64 + n * 16 + (lane & 15)) * 40 + (lane >> 4) * 8]);
#pragma unroll
    for (int m = 0; m < 4; ++m)
#pragma unroll
      for (int n = 0; n < 4; ++n)
        acc[m][n] = __builtin_amdgcn_mfma_f32_16x16x32_bf16(af[m], bf[n], acc[m][n], 0, 0, 0);
  }
  const int rbase = bm * 128 + wr * 64 + ((lane >> 4) << 2);
  const int cbase = bn * 128 + wc * 64 + (lane & 15);
#pragma unroll
  for (int m = 0; m < 4; ++m) {
#pragma unroll
    for (int n = 0; n < 4; ++n) {
#pragma unroll
      for (int j = 0; j < 4; ++j) {
        const int r = rbase + m * 16 + j;
        const int c = cbase + n * 16;
        float v = acc[m][n][j] + bias[c];
        if (RES) v += res[(size_t)r * N + c];
        if (RELU) v = fmaxf(v, 0.0f);
        if (OBF16) Cb[(size_t)r * N + c] = (short)f2bf(v);
        else       Cf[(size_t)r * N + c] = v;
      }
    }
  }
}

// ---------------- causal flash attention: DH=64, 64-row Q tiles ----------------
__global__ __launch_bounds__(256)
void flash_attn(const short* __restrict__ q, const short* __restrict__ k,
                const short* __restrict__ v, short* __restrict__ o) {
  __shared__ short Qs[64 * 72];
  __shared__ short Ks[64 * 72];
  __shared__ short Vt[64 * 72];
  __shared__ short Ps[4 * 16 * 72];
  const int t = threadIdx.x, lane = t & 63, w = t >> 6;
  const int qt = blockIdx.x, bh = blockIdx.y;
  const int b = bh >> 4, hh = bh & 15;
  const int ldr = t >> 3, lc = (t & 7) * 8;
  const float NEG_INF = -__builtin_inff();
  const size_t base_bh = (size_t)b * 2048 * 1024 + hh * 64;
  {
    const size_t qoff = base_bh + (size_t)(qt * 64) * 1024;
#pragma unroll
    for (int p = 0; p < 2; ++p) {
      bh8 vq = *(const bh8*)(q + qoff + (size_t)(p * 32 + ldr) * 1024 + lc);
      *(bh8*)(&Qs[(p * 32 + ldr) * 72 + lc]) = vq;
    }
  }
  f4 Ofr[4] = {};
  float mr[4] = {NEG_INF, NEG_INF, NEG_INF, NEG_INF};
  float lsum[4] = {0.f, 0.f, 0.f, 0.f};

  for (int kt = 0; kt <= qt; ++kt) {
    __syncthreads();
    const size_t koff = base_bh + (size_t)(kt * 64) * 1024;
#pragma unroll
    for (int p = 0; p < 2; ++p) {
      bh8 vk = *(const bh8*)(k + koff + (size_t)(p * 32 + ldr) * 1024 + lc);
      *(bh8*)(&Ks[(p * 32 + ldr) * 72 + lc]) = vk;
      bh8 vv = *(const bh8*)(v + koff + (size_t)(p * 32 + ldr) * 1024 + lc);
#pragma unroll
      for (int i = 0; i < 8; ++i) Vt[(lc + i) * 72 + p * 32 + ldr] = vv[i];
    }
    __syncthreads();
    // S = Q K^T
    f4 sf[4] = {};
#pragma unroll
    for (int kk = 0; kk < 2; ++kk) {
      bh8 aq = *(const bh8*)(&Qs[(w * 16 + (lane & 15)) * 72 + kk * 32 + (lane >> 4) * 8]);
#pragma unroll
      for (int n = 0; n < 4; ++n) {
        bh8 bk = *(const bh8*)(&Ks[(n * 16 + (lane & 15)) * 72 + kk * 32 + (lane >> 4) * 8]);
        sf[n] = __builtin_amdgcn_mfma_f32_16x16x32_bf16(aq, bk, sf[n], 0, 0, 0);
      }
    }
    const float scale = 0.125f;
    if (kt == qt) {
#pragma unroll
      for (int n = 0; n < 4; ++n) {
        const int kp = n * 16 + (lane & 15);
#pragma unroll
        for (int j = 0; j < 4; ++j) {
          const int qp = w * 16 + ((lane >> 4) << 2) + j;
          sf[n][j] = (kp > qp) ? NEG_INF : sf[n][j] * scale;
        }
      }
    } else {
#pragma unroll
      for (int n = 0; n < 4; ++n)
#pragma unroll
        for (int j = 0; j < 4; ++j) sf[n][j] *= scale;
    }
    // online softmax, rows live in 16-lane groups
    float tm[4], al[4], rs[4];
#pragma unroll
    for (int j = 0; j < 4; ++j) {
      float mx = fmaxf(fmaxf(sf[0][j], sf[1][j]), fmaxf(sf[2][j], sf[3][j]));
#pragma unroll
      for (int mk = 1; mk < 16; mk <<= 1) mx = fmaxf(mx, __shfl_xor(mx, mk, 64));
      tm[j] = mx;
    }
#pragma unroll
    for (int j = 0; j < 4; ++j) {
      const float mn = fmaxf(mr[j], tm[j]);
      al[j] = __expf(mr[j] - mn);
      mr[j] = mn;
      rs[j] = 0.f;
    }
    f4 pf[4];
#pragma unroll
    for (int n = 0; n < 4; ++n)
#pragma unroll
      for (int j = 0; j < 4; ++j) {
        const float p = __expf(sf[n][j] - mr[j]);
        pf[n][j] = p;
        rs[j] += p;
      }
#pragma unroll
    for (int j = 0; j < 4; ++j) {
      float s = rs[j];
#pragma unroll
      for (int mk = 1; mk < 16; mk <<= 1) s += __shfl_xor(s, mk, 64);
      lsum[j] = lsum[j] * al[j] + s;
    }
#pragma unroll
    for (int n = 0; n < 4; ++n)
#pragma unroll
      for (int j = 0; j < 4; ++j) Ofr[n][j] *= al[j];
    // P -> LDS (per-wave) to reach A-fragment layout
    short* Pw = &Ps[w * 16 * 72];
#pragma unroll
    for (int n = 0; n < 4; ++n)
#pragma unroll
      for (int j = 0; j < 4; ++j)
        Pw[(((lane >> 4) << 2) + j) * 72 + n * 16 + (lane & 15)] = (short)f2bf(pf[n][j]);
    // O += P V
#pragma unroll
    for (int kk = 0; kk < 2; ++kk) {
      bh8 ap = *(const bh8*)(&Pw[(lane & 15) * 72 + kk * 32 + (lane >> 4) * 8]);
#pragma unroll
      for (int n = 0; n < 4; ++n) {
        bh8 bv = *(const bh8*)(&Vt[(n * 16 + (lane & 15)) * 72 + kk * 32 + (lane >> 4) * 8]);
        Ofr[n] = __builtin_amdgcn_mfma_f32_16x16x32_bf16(ap, bv, Ofr[n], 0, 0, 0);
      }
    }
  }
#pragma unroll
  for (int j = 0; j < 4; ++j) lsum[j] = 1.0f / lsum[j];
  const size_t orow0 = (size_t)b * 2048 + qt * 64 + w * 16 + ((lane >> 4) << 2);
#pragma unroll
  for (int n = 0; n < 4; ++n) {
    const int c = hh * 64 + n * 16 + (lane & 15);
#pragma unroll
    for (int j = 0; j < 4; ++j)
      o[(orow0 + j) * 1024 + c] = (short)f2bf(Ofr[n][j] * lsum[j]);
  }
}

extern "C" void kernel_launch(void* const* d_in, const int* in_sizes, int n_in,
                              void* d_out, int out_size, void* d_ws, size_t ws_size,
                              hipStream_t stream) {
  const float* x   = (const float*)d_in[0];
  const float* Wq  = (const float*)d_in[1];
  const float* bq  = (const float*)d_in[2];
  const float* Wk  = (const float*)d_in[3];
  const float* bk  = (const float*)d_in[4];
  const float* Wv  = (const float*)d_in[5];
  const float* bv  = (const float*)d_in[6];
  const float* Wo  = (const float*)d_in[7];
  const float* bo  = (const float*)d_in[8];
  const float* W1  = (const float*)d_in[9];
  const float* bf1 = (const float*)d_in[10];
  const float* W2  = (const float*)d_in[11];
  const float* bf2 = (const float*)d_in[12];
  const float* g1  = (const float*)d_in[13];
  const float* be1 = (const float*)d_in[14];
  const float* g2  = (const float*)d_in[15];
  const float* be2 = (const float*)d_in[16];
  float* out = (float*)d_out;

  char* ws = (char*)d_ws;
  const size_t MB = 1u << 20;
  short* h   = (short*)(ws);                 // 16 MB: LN output (reused for LN2)
  short* wqb = (short*)(ws + 16 * MB);       // 2 MB each
  short* wkb = (short*)(ws + 18 * MB);
  short* wvb = (short*)(ws + 20 * MB);
  short* wob = (short*)(ws + 22 * MB);
  short* w1b = (short*)(ws + 24 * MB);       // 8 MB
  short* w2b = (short*)(ws + 32 * MB);       // 8 MB
  short* qb  = (short*)(ws + 40 * MB);       // 16 MB
  short* kb  = (short*)(ws + 56 * MB);       // 16 MB
  short* vb  = (short*)(ws + 72 * MB);       // 16 MB
  short* ob  = (short*)(ws + 88 * MB);       // 16 MB
  short* f1  = (short*)(ws + 40 * MB);       // 64 MB, aliases qb..ob (dead by then)
  float* ct  = (float*)(ws + 104 * MB);      // 256 KB
  float* st  = (float*)(ws + 104 * MB + 262144);
  float* x2  = out;                          // attention residual lives in d_out

  rope_table<<<256, 256, 0, stream>>>(ct, st);
  w2bf<<<1024, 256, 0, stream>>>(Wq, wqb, 1024 * 1024);
  w2bf<<<1024, 256, 0, stream>>>(Wk, wkb, 1024 * 1024);
  w2bf<<<1024, 256, 0, stream>>>(Wv, wvb, 1024 * 1024);
  w2bf<<<1024, 256, 0, stream>>>(Wo, wob, 1024 * 1024);
  w2bf<<<4096, 256, 0, stream>>>(W1, w1b, 4096 * 1024);
  w2bf<<<4096, 256, 0, stream>>>(W2, w2b, 4096 * 1024);

  layernorm_bf<<<8192, 256, 0, stream>>>(x, g1, be1, h);

  gemm_bt<0, 0, 1><<<dim3(64, 8), 256, 0, stream>>>(h, wqb, bq, nullptr, qb, nullptr, 8192, 1024, 1024);
  gemm_bt<0, 0, 1><<<dim3(64, 8), 256, 0, stream>>>(h, wkb, bk, nullptr, kb, nullptr, 8192, 1024, 1024);
  gemm_bt<0, 0, 1><<<dim3(64, 8), 256, 0, stream>>>(h, wvb, bv, nullptr, vb, nullptr, 8192, 1024, 1024);

  rope_apply<<<4096, 256, 0, stream>>>(qb, ct, st);
  rope_apply<<<4096, 256, 0, stream>>>(kb, ct, st);

  flash_attn<<<dim3(32, 64), 256, 0, stream>>>(qb, kb, vb, ob);

  gemm_bt<0, 1, 0><<<dim3(64, 8), 256, 0, stream>>>(ob, wob, bo, x, nullptr, x2, 8192, 1024, 1024);

  layernorm_bf<<<8192, 256, 0, stream>>>(x2, g2, be2, h);

  gemm_bt<1, 0, 1><<<dim3(64, 32), 256, 0, stream>>>(h, w1b, bf1, nullptr, f1, nullptr, 8192, 4096, 1024);

  gemm_bt<0, 1, 0><<<dim3(64, 8), 256, 0, stream>>>(f1, w2b, bf2, x2, nullptr, out, 8192, 1024, 4096);
}

// Round 2
// 594.724 us; speedup vs baseline: 1.1752x; 1.1752x over previous
//
#include <hip/hip_runtime.h>

typedef __attribute__((ext_vector_type(8))) short bh8;
typedef __attribute__((ext_vector_type(4))) float f4;

__device__ __forceinline__ unsigned short f2bf(float x) {
  unsigned int u = __float_as_uint(x);
  u += 0x7fffu + ((u >> 16) & 1u);
  return (unsigned short)(u >> 16);
}
__device__ __forceinline__ float bf2f(short x) {
  return __uint_as_float(((unsigned int)(unsigned short)x) << 16);
}
__device__ __forceinline__ void gl_lds16(const short* g, short* l) {
  __builtin_amdgcn_global_load_lds(
      (const __attribute__((address_space(1))) unsigned int*)g,
      (__attribute__((address_space(3))) unsigned int*)l, 16, 0, 0);
}

// ---------------- RoPE table ----------------
__global__ __launch_bounds__(256)
void rope_table(float* __restrict__ ct, float* __restrict__ st) {
  const int idx = blockIdx.x * 256 + threadIdx.x;   // 65536 = 2048*32
  const int s = idx >> 5, j = idx & 31;
  const float invf = expf(-0.28782313662425574f * (float)j);  // 10000^(-j/32)
  const float f = (float)s * invf;
  ct[idx] = cosf(f);
  st[idx] = sinf(f);
}

// ---------------- all weights fp32 -> bf16 in one launch ----------------
__global__ __launch_bounds__(256)
void w2bf_all(const float* __restrict__ Wq, const float* __restrict__ Wk,
              const float* __restrict__ Wv, const float* __restrict__ Wo,
              const float* __restrict__ W1, const float* __restrict__ W2,
              short* __restrict__ wqb, short* __restrict__ wkb,
              short* __restrict__ wvb, short* __restrict__ wob,
              short* __restrict__ w1b, short* __restrict__ w2b) {
  const int which = blockIdx.y;
  const float* src; short* dst; int n;
  switch (which) {
    case 0: src = Wq; dst = wqb; n = 1 << 20; break;
    case 1: src = Wk; dst = wkb; n = 1 << 20; break;
    case 2: src = Wv; dst = wvb; n = 1 << 20; break;
    case 3: src = Wo; dst = wob; n = 1 << 20; break;
    case 4: src = W1; dst = w1b; n = 1 << 22; break;
    default: src = W2; dst = w2b; n = 1 << 22; break;
  }
  const int i = (blockIdx.x * 256 + threadIdx.x) * 4;
  if (i >= n) return;
  f4 v = *(const f4*)(src + i);
#pragma unroll
  for (int j = 0; j < 4; ++j) dst[i + j] = (short)f2bf(v[j]);
}

// ---------------- LayerNorm (row=1024) ----------------
__global__ __launch_bounds__(256)
void layernorm_bf(const float* __restrict__ x, const float* __restrict__ g,
                  const float* __restrict__ be, short* __restrict__ out) {
  __shared__ float sb[4];
  const int row = blockIdx.x, t = threadIdx.x;
  const float* xr = x + (size_t)row * 1024;
  f4 v = *(const f4*)(xr + t * 4);
  float s = v[0] + v[1] + v[2] + v[3];
#pragma unroll
  for (int mk = 1; mk < 64; mk <<= 1) s += __shfl_xor(s, mk, 64);
  if ((t & 63) == 0) sb[t >> 6] = s;
  __syncthreads();
  const float mean = (sb[0] + sb[1] + sb[2] + sb[3]) * (1.0f / 1024.0f);
  __syncthreads();
  f4 d;
#pragma unroll
  for (int i = 0; i < 4; ++i) d[i] = v[i] - mean;
  float s2 = d[0] * d[0] + d[1] * d[1] + d[2] * d[2] + d[3] * d[3];
#pragma unroll
  for (int mk = 1; mk < 64; mk <<= 1) s2 += __shfl_xor(s2, mk, 64);
  if ((t & 63) == 0) sb[t >> 6] = s2;
  __syncthreads();
  const float var = (sb[0] + sb[1] + sb[2] + sb[3]) * (1.0f / 1024.0f);
  const float rstd = rsqrtf(var + 1e-5f);
  const f4 gg = *(const f4*)(g + t * 4);
  const f4 bb = *(const f4*)(be + t * 4);
#pragma unroll
  for (int i = 0; i < 4; ++i)
    out[(size_t)row * 1024 + t * 4 + i] = (short)f2bf(d[i] * rstd * gg[i] + bb[i]);
}

// ---------------- in-place RoPE on q and k (bf16 [8192,1024] each) ----------------
__global__ __launch_bounds__(256)
void rope_apply(short* __restrict__ qb, short* __restrict__ kb,
                const float* __restrict__ ct, const float* __restrict__ st) {
  short* qk = blockIdx.y ? kb : qb;
  const int gid = blockIdx.x * 256 + threadIdx.x;  // 8192*128
  const int row = gid >> 7, chn = gid & 127;
  const int srow = row & 2047;
  const int col = chn * 8;
  const int j0 = (col & 63) >> 1;
  bh8 vv = *(const bh8*)(qk + (size_t)row * 1024 + col);
  bh8 r;
#pragma unroll
  for (int p = 0; p < 4; ++p) {
    const float e = bf2f(vv[2 * p]), od = bf2f(vv[2 * p + 1]);
    const float c = ct[srow * 32 + j0 + p], sn = st[srow * 32 + j0 + p];
    r[2 * p]     = (short)f2bf(e * c - od * sn);
    r[2 * p + 1] = (short)f2bf(e * sn + od * c);
  }
  *(bh8*)(qk + (size_t)row * 1024 + col) = r;
}

// ---------------- V transpose: v[b,s,h,d] -> vt[b,h,d,s] ----------------
__global__ __launch_bounds__(256)
void v_transpose(const short* __restrict__ v, short* __restrict__ vt) {
  __shared__ short tile[64][72];
  const int st = blockIdx.x, bh = blockIdx.y;
  const int b = bh >> 4, hh = bh & 15;
  const int t = threadIdx.x;
  const int r = t >> 3, c = (t & 7) * 8;
#pragma unroll
  for (int p = 0; p < 2; ++p) {
    const int s = st * 64 + p * 32 + r;
    bh8 vv = *(const bh8*)(v + ((size_t)b * 2048 + s) * 1024 + hh * 64 + c);
    *(bh8*)(&tile[p * 32 + r][c]) = vv;
  }
  __syncthreads();
#pragma unroll
  for (int p = 0; p < 2; ++p) {
    const int d = p * 32 + r;
    bh8 ov;
#pragma unroll
    for (int i = 0; i < 8; ++i) ov[i] = tile[c + i][d];
    *(bh8*)(vt + ((size_t)bh * 64 + d) * 2048 + st * 64 + c) = ov;
  }
}

// ---------------- bf16 B^T GEMM (m97 structure): C = A[M,K]*Bw[N,K]^T + bias (+res)(+relu) ----------------
template <int RELU, int RES, int OBF16>
__global__ __launch_bounds__(256)
void gemm_bt(const short* __restrict__ A, const short* __restrict__ Bw,
             const float* __restrict__ bias, const float* __restrict__ res,
             short* __restrict__ Cb, float* __restrict__ Cf,
             int M, int N, int K) {
  __shared__ short As[128 * 32];
  __shared__ short Bs[128 * 32];
  const int t = threadIdx.x;
  const int lane = t & 63;
  const int w = t >> 6, wr = w >> 1, wc = w & 1;
  const int bm = blockIdx.x, bn = blockIdx.y;
  const int srow = lane >> 2;          // 0..15
  const int scol = (lane & 3) * 8;     // shorts
  f4 acc[4][4] = {};
  const short* Abase = A + (size_t)(bm * 128) * K;
  const short* Bbase = Bw + (size_t)(bn * 128) * K;
  for (int kt = 0; kt < K; kt += 32) {
#pragma unroll
    for (int i = 0; i < 2; ++i) {
      const int r = w * 32 + i * 16 + srow;
      gl_lds16(Abase + (size_t)r * K + kt + scol, &As[(w * 32 + i * 16) * 32]);
      gl_lds16(Bbase + (size_t)r * K + kt + scol, &Bs[(w * 32 + i * 16) * 32]);
    }
    __syncthreads();
    bh8 af[4], bf[4];
#pragma unroll
    for (int m = 0; m < 4; ++m)
      af[m] = *(const bh8*)(&As[(wr * 64 + m * 16 + (lane & 15)) * 32 + (lane >> 4) * 8]);
#pragma unroll
    for (int n = 0; n < 4; ++n)
      bf[n] = *(const bh8*)(&Bs[(wc * 64 + n * 16 + (lane & 15)) * 32 + (lane >> 4) * 8]);
#pragma unroll
    for (int m = 0; m < 4; ++m)
#pragma unroll
      for (int n = 0; n < 4; ++n)
        acc[m][n] = __builtin_amdgcn_mfma_f32_16x16x32_bf16(af[m], bf[n], acc[m][n], 0, 0, 0);
    __syncthreads();
  }
  const int rbase = bm * 128 + wr * 64 + ((lane >> 4) << 2);
  const int cbase = bn * 128 + wc * 64 + (lane & 15);
#pragma unroll
  for (int m = 0; m < 4; ++m) {
#pragma unroll
    for (int n = 0; n < 4; ++n) {
#pragma unroll
      for (int j = 0; j < 4; ++j) {
        const int r = rbase + m * 16 + j;
        const int c = cbase + n * 16;
        float v = acc[m][n][j] + bias[c];
        if (RES) v += res[(size_t)r * N + c];
        if (RELU) v = fmaxf(v, 0.0f);
        if (OBF16) Cb[(size_t)r * N + c] = (short)f2bf(v);
        else       Cf[(size_t)r * N + c] = v;
      }
    }
  }
}

// ---------------- causal flash attention: DH=64, 64-row Q tiles, V pre-transposed ----------------
__global__ __launch_bounds__(256)
void flash_attn(const short* __restrict__ q, const short* __restrict__ k,
                const short* __restrict__ vt, short* __restrict__ o) {
  __shared__ short Qs[64 * 72];
  __shared__ short Ks[64 * 72];
  __shared__ short Vs[64 * 72];   // rows = d, cols = kv index
  __shared__ short Ps[4 * 16 * 72];
  const int t = threadIdx.x, lane = t & 63, w = t >> 6;
  const int qt = blockIdx.x, bh = blockIdx.y;
  const int b = bh >> 4, hh = bh & 15;
  const int ldr = t >> 3, lc = (t & 7) * 8;
  const float NEG_INF = -__builtin_inff();
  const size_t base_bh = (size_t)b * 2048 * 1024 + hh * 64;
  const size_t vt_bh = (size_t)bh * 64 * 2048;
  {
    const size_t qoff = base_bh + (size_t)(qt * 64) * 1024;
#pragma unroll
    for (int p = 0; p < 2; ++p) {
      bh8 vq = *(const bh8*)(q + qoff + (size_t)(p * 32 + ldr) * 1024 + lc);
      *(bh8*)(&Qs[(p * 32 + ldr) * 72 + lc]) = vq;
    }
  }
  f4 Ofr[4] = {};
  float mr[4] = {NEG_INF, NEG_INF, NEG_INF, NEG_INF};
  float lsum[4] = {0.f, 0.f, 0.f, 0.f};

  for (int kt = 0; kt <= qt; ++kt) {
    __syncthreads();
    const size_t koff = base_bh + (size_t)(kt * 64) * 1024;
#pragma unroll
    for (int p = 0; p < 2; ++p) {
      bh8 vk = *(const bh8*)(k + koff + (size_t)(p * 32 + ldr) * 1024 + lc);
      *(bh8*)(&Ks[(p * 32 + ldr) * 72 + lc]) = vk;
      bh8 vv = *(const bh8*)(vt + vt_bh + (size_t)(p * 32 + ldr) * 2048 + kt * 64 + lc);
      *(bh8*)(&Vs[(p * 32 + ldr) * 72 + lc]) = vv;
    }
    __syncthreads();
    // S = Q K^T
    f4 sf[4] = {};
#pragma unroll
    for (int kk = 0; kk < 2; ++kk) {
      bh8 aq = *(const bh8*)(&Qs[(w * 16 + (lane & 15)) * 72 + kk * 32 + (lane >> 4) * 8]);
#pragma unroll
      for (int n = 0; n < 4; ++n) {
        bh8 bk = *(const bh8*)(&Ks[(n * 16 + (lane & 15)) * 72 + kk * 32 + (lane >> 4) * 8]);
        sf[n] = __builtin_amdgcn_mfma_f32_16x16x32_bf16(aq, bk, sf[n], 0, 0, 0);
      }
    }
    const float scale = 0.125f;
    if (kt == qt) {
#pragma unroll
      for (int n = 0; n < 4; ++n) {
        const int kp = n * 16 + (lane & 15);
#pragma unroll
        for (int j = 0; j < 4; ++j) {
          const int qp = w * 16 + ((lane >> 4) << 2) + j;
          sf[n][j] = (kp > qp) ? NEG_INF : sf[n][j] * scale;
        }
      }
    } else {
#pragma unroll
      for (int n = 0; n < 4; ++n)
#pragma unroll
        for (int j = 0; j < 4; ++j) sf[n][j] *= scale;
    }
    // online softmax, rows live in 16-lane groups
    float tm[4], al[4], rs[4];
#pragma unroll
    for (int j = 0; j < 4; ++j) {
      float mx = fmaxf(fmaxf(sf[0][j], sf[1][j]), fmaxf(sf[2][j], sf[3][j]));
#pragma unroll
      for (int mk = 1; mk < 16; mk <<= 1) mx = fmaxf(mx, __shfl_xor(mx, mk, 64));
      tm[j] = mx;
    }
#pragma unroll
    for (int j = 0; j < 4; ++j) {
      const float mn = fmaxf(mr[j], tm[j]);
      al[j] = __expf(mr[j] - mn);
      mr[j] = mn;
      rs[j] = 0.f;
    }
    f4 pf[4];
#pragma unroll
    for (int n = 0; n < 4; ++n)
#pragma unroll
      for (int j = 0; j < 4; ++j) {
        const float p = __expf(sf[n][j] - mr[j]);
        pf[n][j] = p;
        rs[j] += p;
      }
#pragma unroll
    for (int j = 0; j < 4; ++j) {
      float s = rs[j];
#pragma unroll
      for (int mk = 1; mk < 16; mk <<= 1) s += __shfl_xor(s, mk, 64);
      lsum[j] = lsum[j] * al[j] + s;
    }
#pragma unroll
    for (int n = 0; n < 4; ++n)
#pragma unroll
      for (int j = 0; j < 4; ++j) Ofr[n][j] *= al[j];
    // P -> LDS (per-wave) to reach A-fragment layout
    short* Pw = &Ps[w * 16 * 72];
#pragma unroll
    for (int n = 0; n < 4; ++n)
#pragma unroll
      for (int j = 0; j < 4; ++j)
        Pw[(((lane >> 4) << 2) + j) * 72 + n * 16 + (lane & 15)] = (short)f2bf(pf[n][j]);
    // O += P V
#pragma unroll
    for (int kk = 0; kk < 2; ++kk) {
      bh8 ap = *(const bh8*)(&Pw[(lane & 15) * 72 + kk * 32 + (lane >> 4) * 8]);
#pragma unroll
      for (int n = 0; n < 4; ++n) {
        bh8 bv = *(const bh8*)(&Vs[(n * 16 + (lane & 15)) * 72 + kk * 32 + (lane >> 4) * 8]);
        Ofr[n] = __builtin_amdgcn_mfma_f32_16x16x32_bf16(ap, bv, Ofr[n], 0, 0, 0);
      }
    }
  }
#pragma unroll
  for (int j = 0; j < 4; ++j) lsum[j] = 1.0f / lsum[j];
  const size_t orow0 = (size_t)b * 2048 + qt * 64 + w * 16 + ((lane >> 4) << 2);
#pragma unroll
  for (int n = 0; n < 4; ++n) {
    const int c = hh * 64 + n * 16 + (lane & 15);
#pragma unroll
    for (int j = 0; j < 4; ++j)
      o[(orow0 + j) * 1024 + c] = (short)f2bf(Ofr[n][j] * lsum[j]);
  }
}

extern "C" void kernel_launch(void* const* d_in, const int* in_sizes, int n_in,
                              void* d_out, int out_size, void* d_ws, size_t ws_size,
                              hipStream_t stream) {
  const float* x   = (const float*)d_in[0];
  const float* Wq  = (const float*)d_in[1];
  const float* bq  = (const float*)d_in[2];
  const float* Wk  = (const float*)d_in[3];
  const float* bk  = (const float*)d_in[4];
  const float* Wv  = (const float*)d_in[5];
  const float* bv  = (const float*)d_in[6];
  const float* Wo  = (const float*)d_in[7];
  const float* bo  = (const float*)d_in[8];
  const float* W1  = (const float*)d_in[9];
  const float* bf1 = (const float*)d_in[10];
  const float* W2  = (const float*)d_in[11];
  const float* bf2 = (const float*)d_in[12];
  const float* g1  = (const float*)d_in[13];
  const float* be1 = (const float*)d_in[14];
  const float* g2  = (const float*)d_in[15];
  const float* be2 = (const float*)d_in[16];
  float* out = (float*)d_out;

  char* ws = (char*)d_ws;
  const size_t MB = 1u << 20;
  short* h   = (short*)(ws);                 // 16 MB: LN output; later vt; later LN2 out
  short* vtb = (short*)(ws);                 // vt aliases h (dead after QKV gemms)
  short* wqb = (short*)(ws + 16 * MB);       // 2 MB each
  short* wkb = (short*)(ws + 18 * MB);
  short* wvb = (short*)(ws + 20 * MB);
  short* wob = (short*)(ws + 22 * MB);
  short* w1b = (short*)(ws + 24 * MB);       // 8 MB
  short* w2b = (short*)(ws + 32 * MB);       // 8 MB
  short* qb  = (short*)(ws + 40 * MB);       // 16 MB
  short* kb  = (short*)(ws + 56 * MB);       // 16 MB
  short* vb  = (short*)(ws + 72 * MB);       // 16 MB
  short* ob  = (short*)(ws + 88 * MB);       // 16 MB
  short* f1  = (short*)(ws + 40 * MB);       // 64 MB, aliases qb..ob (dead by then)
  float* ct  = (float*)(ws + 104 * MB);      // 256 KB
  float* st  = (float*)(ws + 104 * MB + 262144);
  float* x2  = out;                          // attention residual lives in d_out

  rope_table<<<256, 256, 0, stream>>>(ct, st);
  w2bf_all<<<dim3(4096, 6), 256, 0, stream>>>(Wq, Wk, Wv, Wo, W1, W2,
                                              wqb, wkb, wvb, wob, w1b, w2b);

  layernorm_bf<<<8192, 256, 0, stream>>>(x, g1, be1, h);

  gemm_bt<0, 0, 1><<<dim3(64, 8), 256, 0, stream>>>(h, wqb, bq, nullptr, qb, nullptr, 8192, 1024, 1024);
  gemm_bt<0, 0, 1><<<dim3(64, 8), 256, 0, stream>>>(h, wkb, bk, nullptr, kb, nullptr, 8192, 1024, 1024);
  gemm_bt<0, 0, 1><<<dim3(64, 8), 256, 0, stream>>>(h, wvb, bv, nullptr, vb, nullptr, 8192, 1024, 1024);

  rope_apply<<<dim3(4096, 2), 256, 0, stream>>>(qb, kb, ct, st);

  v_transpose<<<dim3(32, 64), 256, 0, stream>>>(vb, vtb);   // h is dead now

  flash_attn<<<dim3(32, 64), 256, 0, stream>>>(qb, kb, vtb, ob);

  gemm_bt<0, 1, 0><<<dim3(64, 8), 256, 0, stream>>>(ob, wob, bo, x, nullptr, x2, 8192, 1024, 1024);

  layernorm_bf<<<8192, 256, 0, stream>>>(x2, g2, be2, h);   // vt dead now

  gemm_bt<1, 0, 1><<<dim3(64, 32), 256, 0, stream>>>(h, w1b, bf1, nullptr, f1, nullptr, 8192, 4096, 1024);

  gemm_bt<0, 1, 0><<<dim3(64, 8), 256, 0, stream>>>(f1, w2b, bf2, x2, nullptr, out, 8192, 1024, 4096);
}